// Round 8
// baseline (659.377 us; speedup 1.0000x reference)
//
#include <hip/hip_runtime.h>
#include <hip/hip_bf16.h>

// MultiHeadAttentionLayer: B=2 S=2048 D=1024 H=16 DK=64
// Round 8:
//   attn restructured: pass1 = FA-2 online (split QK once + PV with alpha
//   rescale) -> O and z=m+log2(l). pass2 = atp only, PLAIN bf16 QK (8 MFMA/kt)
//   with p=exp2(s-z); atp is absolute-error tolerant. Ps packed bf16 via
//   lane-pair shfl (dword writes) -> LDS 54.3 KB -> 3 blocks/CU.

#define B_  2
#define S_  2048
#define D_  1024
#define H_  16
#define DK_ 64

typedef __bf16 bf16x8 __attribute__((ext_vector_type(8)));
typedef __bf16 bf16x2 __attribute__((ext_vector_type(2)));
typedef float f32x4  __attribute__((ext_vector_type(4)));

__device__ __forceinline__ void ld_g2l16(const __bf16* g, __bf16* l) {
  __builtin_amdgcn_global_load_lds(
      (const __attribute__((address_space(1))) void*)g,
      (__attribute__((address_space(3))) void*)l, 16, 0, 0);
}

// ------------------------------------------------------------ converts ----
__device__ __forceinline__ void split3_body(const float* __restrict__ x,
                                            __bf16* __restrict__ y,
                                            int lbid, int tid, int mode)
{
  int i = (lbid * 256 + tid) * 8;
  float4 a = *(const float4*)(x + i);
  float4 b = *(const float4*)(x + i + 4);
  float xs[8] = {a.x, a.y, a.z, a.w, b.x, b.y, b.z, b.w};
  __bf16 out[24];
#pragma unroll
  for (int j = 0; j < 8; j++) {
    float v = xs[j];
    __bf16 hi = (__bf16)v;
    __bf16 lo = (__bf16)(v - (float)hi);
    if (mode == 0) { out[3*j] = hi; out[3*j+1] = hi; out[3*j+2] = lo; }
    else           { out[3*j] = hi; out[3*j+1] = lo; out[3*j+2] = hi; }
  }
  *(bf16x8*)(y + 3 * (size_t)i)      = *(bf16x8*)&out[0];
  *(bf16x8*)(y + 3 * (size_t)i + 8)  = *(bf16x8*)&out[8];
  *(bf16x8*)(y + 3 * (size_t)i + 16) = *(bf16x8*)&out[16];
}

__device__ __forceinline__ void tobf16_body(const float* __restrict__ x,
                                            __bf16* __restrict__ y,
                                            int lbid, int tid)
{
  int i = (lbid * 256 + tid) * 8;
  float4 a = *(const float4*)(x + i);
  float4 b = *(const float4*)(x + i + 4);
  __bf16 out[8] = {(__bf16)a.x, (__bf16)a.y, (__bf16)a.z, (__bf16)a.w,
                   (__bf16)b.x, (__bf16)b.y, (__bf16)b.z, (__bf16)b.w};
  *(bf16x8*)(y + i) = *(bf16x8*)&out[0];
}

__global__ __launch_bounds__(256)
void convert_all(const float* __restrict__ query, const float* __restrict__ key_,
                 const float* __restrict__ value, const float* __restrict__ Wq,
                 const float* __restrict__ Wk, const float* __restrict__ Wv,
                 const float* __restrict__ Wo, __bf16* __restrict__ qcat3,
                 __bf16* __restrict__ kcat3, __bf16* __restrict__ vxb,
                 __bf16* __restrict__ wqc3, __bf16* __restrict__ wkc3,
                 __bf16* __restrict__ wvb, __bf16* __restrict__ wob,
                 float* __restrict__ atp)
{
  int bid = blockIdx.x, tid = threadIdx.x;
  if (bid < 2048)       split3_body(query, qcat3, bid, tid, 0);
  else if (bid < 4096)  split3_body(key_,  kcat3, bid - 2048, tid, 0);
  else if (bid < 6144)  tobf16_body(value, vxb,   bid - 4096, tid);
  else if (bid < 6656)  split3_body(Wq, wqc3, bid - 6144, tid, 1);
  else if (bid < 7168)  split3_body(Wk, wkc3, bid - 6656, tid, 1);
  else if (bid < 7680)  tobf16_body(Wv, wvb, bid - 7168, tid);
  else if (bid < 8192)  tobf16_body(Wo, wob, bid - 7680, tid);
  else {
    int base = (bid - 8192) * 2048;
#pragma unroll
    for (int j = 0; j < 8; j++) atp[base + j * 256 + tid] = 0.f;
  }
}

// ---------------------------------------------------------- MFMA GEMM ----
#define TM 64
#define TN 128
#define TK 64

__device__ __forceinline__
void gemm_body(const __bf16* __restrict__ X, const __bf16* __restrict__ W,
               const float* __restrict__ bias, void* __restrict__ Y,
               void* __restrict__ Y2, int N, int K, int out_mode, float osf,
               __bf16* Xa, __bf16* Wb, int bx, int by)
{
  const int tid  = threadIdx.x;
  const int lane = tid & 63;
  const int w    = tid >> 6;
  const int c    = lane & 15;
  const int quad = lane >> 4;
  const int row0 = by * TM;
  const int col0 = bx * TN;
  const int wc   = w * 32;

  f32x4 acc[4][2];
#pragma unroll
  for (int i = 0; i < 4; i++)
#pragma unroll
    for (int j = 0; j < 2; j++) acc[i][j] = (f32x4){0.f, 0.f, 0.f, 0.f};

  for (int k0 = 0; k0 < K; k0 += TK) {
    __syncthreads();
#pragma unroll
    for (int i = 0; i < 2; i++) {
      int chunk = i * 256 + w * 64 + lane;
      int r = chunk >> 3, dch = chunk & 7;
      ld_g2l16(X + (size_t)(row0 + r) * K + k0 + dch * 8, &Xa[chunk * 8]);
    }
#pragma unroll
    for (int i = 0; i < 4; i++) {
      int chunk = i * 256 + w * 64 + lane;
      int r = chunk >> 3, dch = chunk & 7;
      ld_g2l16(W + (size_t)(col0 + r) * K + k0 + dch * 8, &Wb[chunk * 8]);
    }
    __syncthreads();

#pragma unroll
    for (int cc = 0; cc < 2; cc++) {
      bf16x8 af[4], bf[2];
#pragma unroll
      for (int i = 0; i < 4; i++)
        af[i] = *(const bf16x8*)&Xa[(i * 16 + c) * TK + cc * 32 + quad * 8];
#pragma unroll
      for (int j = 0; j < 2; j++)
        bf[j] = *(const bf16x8*)&Wb[(wc + j * 16 + c) * TK + cc * 32 + quad * 8];
#pragma unroll
      for (int i = 0; i < 4; i++)
#pragma unroll
        for (int j = 0; j < 2; j++)
          acc[i][j] = __builtin_amdgcn_mfma_f32_16x16x32_bf16(af[i], bf[j],
                                                              acc[i][j], 0, 0, 0);
    }
  }

#pragma unroll
  for (int i = 0; i < 4; i++) {
#pragma unroll
    for (int j = 0; j < 2; j++) {
      int col = col0 + wc + j * 16 + c;
      float bcol = bias[col];
#pragma unroll
      for (int r = 0; r < 4; r++) {
        int row = row0 + i * 16 + quad * 4 + r;
        float v = (acc[i][j][r] + bcol) * osf;
        if (out_mode == 0) {
          ((float*)Y)[(size_t)row * N + col] = v;
        } else {
          int b2 = row >> 11, s = row & (S_ - 1);
          int h = col >> 6, dk = col & 63;
          if (out_mode == 1) {
            size_t off = ((size_t)(b2 * H_ + h) * S_ + s) * DK_ + dk;
            __bf16 hi = (__bf16)v;
            ((__bf16*)Y)[off]  = hi;
            ((__bf16*)Y2)[off] = (__bf16)(v - (float)hi);
          } else {
            ((__bf16*)Y)[((size_t)(b2 * H_ + h) * DK_ + dk) * S_ + s] = (__bf16)v;
          }
        }
      }
    }
  }
}

__global__ __launch_bounds__(256)
void gemm_qkv(const __bf16* __restrict__ qcat3, const __bf16* __restrict__ wqc3,
              const float* __restrict__ bq, __bf16* __restrict__ qh, __bf16* __restrict__ ql,
              const __bf16* __restrict__ kcat3, const __bf16* __restrict__ wkc3,
              const float* __restrict__ bk, __bf16* __restrict__ kh, __bf16* __restrict__ kl,
              const __bf16* __restrict__ vxb, const __bf16* __restrict__ wvb,
              const float* __restrict__ bv, __bf16* __restrict__ vt, float qsf)
{
  __shared__ __align__(16) __bf16 Xa[TM * TK];
  __shared__ __align__(16) __bf16 Wb[TN * TK];
  int z = blockIdx.z;
  if (z == 0)
    gemm_body(qcat3, wqc3, bq, qh, ql, D_, 3 * D_, 1, qsf, Xa, Wb, blockIdx.x, blockIdx.y);
  else if (z == 1)
    gemm_body(kcat3, wkc3, bk, kh, kl, D_, 3 * D_, 1, 1.0f, Xa, Wb, blockIdx.x, blockIdx.y);
  else
    gemm_body(vxb, wvb, bv, vt, nullptr, D_, D_, 2, 1.0f, Xa, Wb, blockIdx.x, blockIdx.y);
}

__global__ __launch_bounds__(256)
void gemm_mfma(const __bf16* __restrict__ X, const __bf16* __restrict__ W,
               const float* __restrict__ bias, void* __restrict__ Y,
               void* __restrict__ Y2, int M, int N, int K, int out_mode,
               float osf)
{
  __shared__ __align__(16) __bf16 Xa[TM * TK];
  __shared__ __align__(16) __bf16 Wb[TN * TK];
  gemm_body(X, W, bias, Y, Y2, N, K, out_mode, osf, Xa, Wb, blockIdx.x, blockIdx.y);
}

// ----------------------------------------------------------- attention ----
// QB=128: 8 waves x 16 rows, 512 threads. q pre-scaled by 12.5*log2(e).
#define LSTR  72   // bf16 row stride for K/V tiles
#define PBSTR 72   // bf16 row stride for P tiles

__global__ __launch_bounds__(512, 6)
void attn_mfma(const __bf16* __restrict__ qh_ws, const __bf16* __restrict__ ql_ws,
               const __bf16* __restrict__ kh_ws, const __bf16* __restrict__ kl_ws,
               const __bf16* __restrict__ vt_ws, __bf16* __restrict__ attn_out,
               float* __restrict__ atp_out)
{
  __shared__ __align__(16) __bf16 Kh[64 * LSTR];     // 9216 B
  __shared__ __align__(16) __bf16 Kl[64 * LSTR];     // 9216 B
  __shared__ __align__(16) __bf16 Vt[64 * LSTR];     // 9216 B
  __shared__ __align__(16) __bf16 Ps[8][16 * PBSTR]; // 18432 B (per-wave bf16 P)
  __shared__ float  atp_lds[S_];                     // 8192 B   -> 54272 total

  const int tid  = threadIdx.x;
  const int lane = tid & 63;
  const int w    = tid >> 6;             // wave 0..7
  const int c    = lane & 15;
  const int quad = lane >> 4;
  const int qb   = blockIdx.x;           // 0..15
  const int h    = blockIdx.y;
  const int b    = blockIdx.z;

  const size_t bh = (size_t)(b * H_ + h);
  const __bf16* qhg = qh_ws + (bh * S_ + qb * 128) * DK_;
  const __bf16* qlg = ql_ws + (bh * S_ + qb * 128) * DK_;
  const __bf16* khg = kh_ws + bh * S_ * DK_;
  const __bf16* klg = kl_ws + bh * S_ * DK_;
  const __bf16* vg  = vt_ws + bh * DK_ * S_;

  bf16x8 qhf[2], qlf[2];
  {
    const __bf16* qrow = qhg + (size_t)(w * 16 + c) * DK_;
    qhf[0] = *(const bf16x8*)(qrow + quad * 8);
    qhf[1] = *(const bf16x8*)(qrow + 32 + quad * 8);
    const __bf16* qrow2 = qlg + (size_t)(w * 16 + c) * DK_;
    qlf[0] = *(const bf16x8*)(qrow2 + quad * 8);
    qlf[1] = *(const bf16x8*)(qrow2 + 32 + quad * 8);
  }

  float m_r[4], l_r[4];
#pragma unroll
  for (int r = 0; r < 4; r++) { m_r[r] = -1e30f; l_r[r] = 0.f; }

  f32x4 of[4];
#pragma unroll
  for (int nt = 0; nt < 4; nt++) of[nt] = (f32x4){0.f, 0.f, 0.f, 0.f};

  __bf16* ps = Ps[w];
  const bool evenc = (c & 1) == 0;
  const int kb2 = c & ~1;                // even key base within 16-col group
  const int rw0 = evenc ? 0 : 2;         // rows this lane packs

  // ------------- pass 1: FA-2 online (split QK once, PV, m/l) -------------
  for (int kt = 0; kt < S_ / 64; kt++) {
    __syncthreads();
    {
      int key = tid >> 3, dch = tid & 7;   // 512 chunks per tile
      size_t goff = (size_t)(kt * 64 + key) * DK_ + dch * 8;
      *(bf16x8*)&Kh[key * LSTR + dch * 8] = *(const bf16x8*)(khg + goff);
      *(bf16x8*)&Kl[key * LSTR + dch * 8] = *(const bf16x8*)(klg + goff);
      *(bf16x8*)&Vt[key * LSTR + dch * 8] =
          *(const bf16x8*)(vg + (size_t)key * S_ + kt * 64 + dch * 8);
    }
    __syncthreads();

    // split-bf16 scores (24 MFMA)
    f32x4 sc[4];
#pragma unroll
    for (int nt = 0; nt < 4; nt++) {
      sc[nt] = (f32x4){0.f, 0.f, 0.f, 0.f};
#pragma unroll
      for (int cc = 0; cc < 2; cc++) {
        bf16x8 bh8 = *(const bf16x8*)&Kh[(nt * 16 + c) * LSTR + cc * 32 + quad * 8];
        bf16x8 bl8 = *(const bf16x8*)&Kl[(nt * 16 + c) * LSTR + cc * 32 + quad * 8];
        sc[nt] = __builtin_amdgcn_mfma_f32_16x16x32_bf16(qhf[cc], bh8, sc[nt], 0, 0, 0);
        sc[nt] = __builtin_amdgcn_mfma_f32_16x16x32_bf16(qhf[cc], bl8, sc[nt], 0, 0, 0);
        sc[nt] = __builtin_amdgcn_mfma_f32_16x16x32_bf16(qlf[cc], bh8, sc[nt], 0, 0, 0);
      }
    }

    // row max
    float tm[4];
#pragma unroll
    for (int r = 0; r < 4; r++)
      tm[r] = fmaxf(fmaxf(sc[0][r], sc[1][r]), fmaxf(sc[2][r], sc[3][r]));
#pragma unroll
    for (int o = 1; o < 16; o <<= 1)
#pragma unroll
      for (int r = 0; r < 4; r++)
        tm[r] = fmaxf(tm[r], __shfl_xor(tm[r], o, 64));

    float alpha[4];
#pragma unroll
    for (int r = 0; r < 4; r++) {
      float mnew = fmaxf(m_r[r], tm[r]);
      alpha[r] = exp2f(m_r[r] - mnew);
      m_r[r] = mnew;
    }

    // p = exp2(s - m), packed-bf16 Ps write, psum
    float psum[4] = {0.f, 0.f, 0.f, 0.f};
#pragma unroll
    for (int nt = 0; nt < 4; nt++) {
      float p[4], pq[4];
#pragma unroll
      for (int r = 0; r < 4; r++) {
        p[r] = exp2f(sc[nt][r] - m_r[r]);
        psum[r] += p[r];
      }
#pragma unroll
      for (int r = 0; r < 4; r++) pq[r] = __shfl_xor(p[r], 1, 64);
      // even lane packs rows 0,1 / odd lane rows 2,3 of (key kb2, kb2+1)
#pragma unroll
      for (int rr = 0; rr < 2; rr++) {
        int r = rw0 + rr;
        bf16x2 pk;
        pk[0] = evenc ? (__bf16)p[r]  : (__bf16)pq[r];
        pk[1] = evenc ? (__bf16)pq[r] : (__bf16)p[r];
        *(bf16x2*)&ps[(quad * 4 + r) * PBSTR + nt * 16 + kb2] = pk;
      }
    }
#pragma unroll
    for (int o = 1; o < 16; o <<= 1)
#pragma unroll
      for (int r = 0; r < 4; r++)
        psum[r] += __shfl_xor(psum[r], o, 64);
#pragma unroll
    for (int r = 0; r < 4; r++) l_r[r] = l_r[r] * alpha[r] + psum[r];

    // O rescale + PV
#pragma unroll
    for (int nt = 0; nt < 4; nt++)
#pragma unroll
      for (int r = 0; r < 4; r++) of[nt][r] *= alpha[r];

    bf16x8 pa[2];
#pragma unroll
    for (int cc = 0; cc < 2; cc++)
      pa[cc] = *(const bf16x8*)&ps[c * PBSTR + cc * 32 + quad * 8];
#pragma unroll
    for (int nt = 0; nt < 4; nt++)
#pragma unroll
      for (int cc = 0; cc < 2; cc++) {
        bf16x8 vb = *(const bf16x8*)&Vt[(nt * 16 + c) * LSTR + cc * 32 + quad * 8];
        of[nt] = __builtin_amdgcn_mfma_f32_16x16x32_bf16(pa[cc], vb, of[nt], 0, 0, 0);
      }
  }

  // finalize O and z
  float z_r[4];
#pragma unroll
  for (int r = 0; r < 4; r++) {
    z_r[r] = m_r[r] + log2f(l_r[r]);
    l_r[r] = 1.0f / l_r[r];
  }
#pragma unroll
  for (int nt = 0; nt < 4; nt++)
#pragma unroll
    for (int r = 0; r < 4; r++)
      attn_out[((size_t)(b * S_ + qb * 128 + w * 16 + quad * 4 + r)) * D_
               + h * DK_ + nt * 16 + c] = (__bf16)(of[nt][r] * l_r[r]);

  for (int i = tid; i < S_; i += 512) atp_lds[i] = 0.f;

  // ------------- pass 2: atp only, plain bf16 QK (8 MFMA/kt) -------------
  for (int kt = 0; kt < S_ / 64; kt++) {
    __syncthreads();
    {
      int key = tid >> 3, dch = tid & 7;
      *(bf16x8*)&Kh[key * LSTR + dch * 8] =
          *(const bf16x8*)(khg + (size_t)(kt * 64 + key) * DK_ + dch * 8);
    }
    __syncthreads();

#pragma unroll
    for (int nt = 0; nt < 4; nt++) {
      f32x4 sc = {0.f, 0.f, 0.f, 0.f};
#pragma unroll
      for (int cc = 0; cc < 2; cc++) {
        bf16x8 bh8 = *(const bf16x8*)&Kh[(nt * 16 + c) * LSTR + cc * 32 + quad * 8];
        sc = __builtin_amdgcn_mfma_f32_16x16x32_bf16(qhf[cc], bh8, sc, 0, 0, 0);
      }
      float t = 0.f;
#pragma unroll
      for (int r = 0; r < 4; r++) t += exp2f(sc[r] - z_r[r]);
      t += __shfl_xor(t, 16, 64);
      t += __shfl_xor(t, 32, 64);
      if (quad == 0) atomicAdd(&atp_lds[kt * 64 + nt * 16 + c], t);
    }
  }

  __syncthreads();
  const float inv = 1.0f / ((float)H_ * (float)S_);
  for (int i = tid; i < S_; i += 512)
    atomicAdd(&atp_out[b * S_ + i], atp_lds[i] * inv);
}

// -------------------------------------------------------------- launch ----
extern "C" void kernel_launch(void* const* d_in, const int* in_sizes, int n_in,
                              void* d_out, int out_size, void* d_ws, size_t ws_size,
                              hipStream_t stream)
{
  const float* query = (const float*)d_in[0];
  const float* key_  = (const float*)d_in[1];
  const float* value = (const float*)d_in[2];
  const float* Wq = (const float*)d_in[3];
  const float* bq = (const float*)d_in[4];
  const float* Wk = (const float*)d_in[5];
  const float* bk = (const float*)d_in[6];
  const float* Wv = (const float*)d_in[7];
  const float* bv = (const float*)d_in[8];
  const float* Wo = (const float*)d_in[9];
  const float* bo = (const float*)d_in[10];

  float* out = (float*)d_out;                       // [B,S,D] flat fp32
  float* atp = out + (size_t)B_ * S_ * D_;          // [B,S]

  const size_t NE = (size_t)B_ * S_ * D_;           // 4M
  const size_t NW = (size_t)D_ * D_;                // 1M
  __bf16* p = (__bf16*)d_ws;
  __bf16* qcat3 = p;               p += 3 * NE;     // dead after Q-GEMM
  __bf16* kcat3 = p;               p += 3 * NE;     // dead after K-GEMM
  __bf16* wqc3  = p;               p += 3 * NW;
  __bf16* wkc3  = p;               p += 3 * NW;
  __bf16* vxb   = p;               p += NE;
  __bf16* wvb   = p;               p += NW;
  __bf16* wob   = p;               p += NW;
  __bf16* qh_ws = p;               p += NE;
  __bf16* ql_ws = p;               p += NE;
  __bf16* kh_ws = p;               p += NE;
  __bf16* kl_ws = p;               p += NE;
  __bf16* vt_ws = kcat3;                            // alias (dead before write)
  __bf16* a_ws  = qcat3;                            // alias (dead before write)

  const int M = B_ * S_;
  const float QSF = 18.0337320f;   // 12.5 * log2(e) -> log2-domain scores

  convert_all<<<8194, 256, 0, stream>>>(query, key_, value, Wq, Wk, Wv, Wo,
                                        qcat3, kcat3, vxb, wqc3, wkc3, wvb, wob,
                                        atp);

  gemm_qkv<<<dim3(D_ / TN, M / TM, 3), 256, 0, stream>>>(
      qcat3, wqc3, bq, qh_ws, ql_ws,
      kcat3, wkc3, bk, kh_ws, kl_ws,
      vxb,   wvb,  bv, vt_ws, QSF);

  attn_mfma<<<dim3(S_ / 128, H_, B_), 512, 0, stream>>>(qh_ws, ql_ws, kh_ws, kl_ws,
                                                        vt_ws, a_ws, atp);

  gemm_mfma<<<dim3(D_ / TN, M / TM), 256, 0, stream>>>(a_ws, wob, bo, out, nullptr,
                                                       M, D_, D_, 0, 1.0f);
}